// Round 1
// baseline (9657.928 us; speedup 1.0000x reference)
//
#include <hip/hip_runtime.h>
#include <hip/hip_bf16.h>

#define B 64
#define L 128
#define E 512
#define H 512
#define V 32000
#define T 64

// ---------- helpers ----------
__device__ __forceinline__ unsigned long long pack_key(float v, int n) {
    unsigned u = __float_as_uint(v);
    u = (u & 0x80000000u) ? ~u : (u | 0x80000000u);   // order-preserving float->uint
    return ((unsigned long long)u << 32) | (unsigned)(~n); // tie -> smaller n wins (numpy argmax)
}

// ---------- kernel 1: h0 = z @ W_proj.T + b_proj; zero argmax slots ----------
__global__ __launch_bounds__(256) void init_kernel(
    const float* __restrict__ z, const float* __restrict__ W_proj,
    const float* __restrict__ b_proj, float* __restrict__ hbuf,
    unsigned long long* __restrict__ slots) {
    int idx = blockIdx.x * 256 + threadIdx.x;       // 128 blocks * 256 = 64*512
    int b = idx >> 9;
    int i = idx & 511;
    const float* zrow = z + b * L;                  // uniform within block
    const float* wrow = W_proj + (size_t)i * L;
    float acc = b_proj[i];
#pragma unroll
    for (int k = 0; k < L; k += 4) {
        float4 zv = *(const float4*)(zrow + k);
        float4 wv = *(const float4*)(wrow + k);
        acc = fmaf(zv.x, wv.x, acc);
        acc = fmaf(zv.y, wv.y, acc);
        acc = fmaf(zv.z, wv.z, acc);
        acc = fmaf(zv.w, wv.w, acc);
    }
    hbuf[b * H + i] = acc;                          // h[0] = h0
    if (idx < 128) slots[idx] = 0ull;               // both slot buffers
}

// ---------- kernel 2: GRU cell ----------
// grid 128, block (64,4). One wave per hidden index i; lanes = batch b.
// x source: slots-fed emb gather (or h0 on step 0).
// Also writes hT[i][b] (transposed h) for the logits kernel's scalar loads.
__global__ __launch_bounds__(256) void gru_kernel(
    const float* __restrict__ hsrc, const float* __restrict__ x0,
    const float* __restrict__ emb, const unsigned long long* __restrict__ sread,
    unsigned long long* __restrict__ sreset,
    const float* __restrict__ W_ih, const float* __restrict__ b_ih,
    const float* __restrict__ W_hh, const float* __restrict__ b_hh,
    float* __restrict__ hdst, float* __restrict__ hTd) {
    __shared__ __align__(16) float xs[64 * 65];     // [kk][b], stride 65 -> conflict-free
    __shared__ __align__(16) float hs[64 * 65];
    int tx = threadIdx.x, ty = threadIdx.y;
    int tid = ty * 64 + tx;
    int i = __builtin_amdgcn_readfirstlane((int)(blockIdx.x * 4 + ty)); // wave-uniform -> scalar W loads
    const float* wih_r = W_ih + (size_t)i * E;
    const float* wih_z = W_ih + (size_t)(H + i) * E;
    const float* wih_n = W_ih + (size_t)(2 * H + i) * E;
    const float* whh_r = W_hh + (size_t)i * H;
    const float* whh_z = W_hh + (size_t)(H + i) * H;
    const float* whh_n = W_hh + (size_t)(2 * H + i) * H;

    float air = 0.f, aiz = 0.f, ain = 0.f, ahr = 0.f, ahz = 0.f, ahn = 0.f;

    for (int k0 = 0; k0 < E; k0 += 64) {
        __syncthreads();
#pragma unroll
        for (int j = 0; j < 4; ++j) {
            int q = tid + j * 256;
            int row = q >> 4;                       // batch row 0..63
            int c4 = q & 15;                        // float4 col within 64-chunk
            const float* xrow;
            if (sread) {
                int id = (int)(~(unsigned)sread[row]);
                xrow = emb + (size_t)id * E;
            } else {
                xrow = x0 + (size_t)row * E;
            }
            float4 xv = *(const float4*)(xrow + k0 + c4 * 4);
            float4 hv = *(const float4*)(hsrc + (size_t)row * H + k0 + c4 * 4);
            int kk = c4 * 4;
            xs[(kk + 0) * 65 + row] = xv.x;
            xs[(kk + 1) * 65 + row] = xv.y;
            xs[(kk + 2) * 65 + row] = xv.z;
            xs[(kk + 3) * 65 + row] = xv.w;
            hs[(kk + 0) * 65 + row] = hv.x;
            hs[(kk + 1) * 65 + row] = hv.y;
            hs[(kk + 2) * 65 + row] = hv.z;
            hs[(kk + 3) * 65 + row] = hv.w;
        }
        __syncthreads();
#pragma unroll 4
        for (int kk = 0; kk < 64; ++kk) {
            float xv = xs[kk * 65 + tx];
            float hv = hs[kk * 65 + tx];
            int k = k0 + kk;
            air = fmaf(xv, wih_r[k], air);
            aiz = fmaf(xv, wih_z[k], aiz);
            ain = fmaf(xv, wih_n[k], ain);
            ahr = fmaf(hv, whh_r[k], ahr);
            ahz = fmaf(hv, whh_z[k], ahz);
            ahn = fmaf(hv, whh_n[k], ahn);
        }
    }
    float ir = air + b_ih[i];
    float iz = aiz + b_ih[H + i];
    float inn = ain + b_ih[2 * H + i];
    float hr = ahr + b_hh[i];
    float hz = ahz + b_hh[H + i];
    float hn = ahn + b_hh[2 * H + i];
    float r  = 1.0f / (1.0f + expf(-(ir + hr)));
    float zg = 1.0f / (1.0f + expf(-(iz + hz)));
    float nn = tanhf(inn + r * hn);
    float hp = hsrc[(size_t)tx * H + i];
    float hval = (1.0f - zg) * nn + zg * hp;
    hdst[(size_t)tx * H + i] = hval;
    hTd[(size_t)i * B + tx] = hval;                 // transposed copy (coalesced: lanes = b)

    if (blockIdx.x == 0 && tid < 64) sreset[tid] = 0ull;  // reset this step's slots before logits
}

// ---------- kernel 3: logits = h_new @ W_fc.T + b_fc ----------
// Restructured: no LDS, no barriers. grid 500, block (64,4) = 4 waves.
// lane tx = output column n within 64-wide tile; wave ty = b-quarter (16 batch rows).
// h comes from hT (transposed) via wave-uniform scalar loads -> SGPRs (scalar pipe);
// W_fc row streams per-lane global->VGPR (L1-resident 64B lines), double-buffered 16-k deep.
// Inner loop is pure v_fmac with SGPR operand: VALU-bound at the fp32 floor.
__global__ __launch_bounds__(256) void logits_kernel(
    const float* __restrict__ hT, const float* __restrict__ W_fc,
    const float* __restrict__ b_fc, float* __restrict__ out,
    int t, unsigned long long* __restrict__ slots) {
    int tx = threadIdx.x;                                        // 0..63 = n offset
    int tyu = __builtin_amdgcn_readfirstlane((int)threadIdx.y);  // 0..3, wave-uniform
    int n = blockIdx.x * 64 + tx;
    const float* wp = W_fc + (size_t)n * H;
    const float* hq = hT + tyu * 16;                             // this wave's b-quarter

    float acc[16];
#pragma unroll
    for (int j = 0; j < 16; ++j) acc[j] = 0.f;

    float4 c0 = *(const float4*)(wp + 0);
    float4 c1 = *(const float4*)(wp + 4);
    float4 c2 = *(const float4*)(wp + 8);
    float4 c3 = *(const float4*)(wp + 12);

    for (int k0 = 0; k0 < H; k0 += 16) {
        int kn = (k0 + 16 < H) ? (k0 + 16) : 0;   // clamp: last prefetch harmless (L1-hot)
        float4 p0 = *(const float4*)(wp + kn + 0);
        float4 p1 = *(const float4*)(wp + kn + 4);
        float4 p2 = *(const float4*)(wp + kn + 8);
        float4 p3 = *(const float4*)(wp + kn + 12);
        float wk[16] = {c0.x, c0.y, c0.z, c0.w, c1.x, c1.y, c1.z, c1.w,
                        c2.x, c2.y, c2.z, c2.w, c3.x, c3.y, c3.z, c3.w};
        const float* hk = hq + (size_t)k0 * B;
#pragma unroll
        for (int kk = 0; kk < 16; ++kk) {
            float w = wk[kk];                      // constant index after unroll -> register
            const float* hp_ = hk + kk * B;        // wave-uniform address -> s_load
#pragma unroll
            for (int j = 0; j < 16; ++j) acc[j] = fmaf(w, hp_[j], acc[j]);
        }
        c0 = p0; c1 = p1; c2 = p2; c3 = p3;
    }

    // epilogue: bias + store + in-register argmax
    float bfc = b_fc[n];
#pragma unroll
    for (int j = 0; j < 16; ++j) acc[j] += bfc;

#pragma unroll
    for (int j = 0; j < 16; ++j) {
        int b = tyu * 16 + j;
        out[((size_t)b * T + t) * (size_t)V + n] = acc[j];  // 64 lanes -> 256B coalesced
    }

    // per-b max over the 64 lanes (n-dim): f32 butterfly + ballot for first-max lane
    unsigned long long mykey = 0ull;
#pragma unroll
    for (int j = 0; j < 16; ++j) {
        float v = acc[j];
        v = fmaxf(v, __shfl_xor(v, 32));
        v = fmaxf(v, __shfl_xor(v, 16));
        v = fmaxf(v, __shfl_xor(v, 8));
        v = fmaxf(v, __shfl_xor(v, 4));
        v = fmaxf(v, __shfl_xor(v, 2));
        v = fmaxf(v, __shfl_xor(v, 1));
        unsigned long long ball = __ballot(acc[j] == v);
        int lane = __ffsll((long long)ball) - 1;             // smallest lane = smallest n (numpy tie)
        unsigned long long key = pack_key(v, blockIdx.x * 64 + lane);
        if (tx == j) mykey = key;                            // lane j carries b-row j's key
    }
    if (tx < 16) {
        unsigned long long* slot = slots + tyu * 16 + tx;
        if (mykey > *slot) atomicMax(slot, mykey);           // read-filter kills contention
    }
}

// ---------- host ----------
extern "C" void kernel_launch(void* const* d_in, const int* in_sizes, int n_in,
                              void* d_out, int out_size, void* d_ws, size_t ws_size,
                              hipStream_t stream) {
    const float* z      = (const float*)d_in[0];
    const float* emb    = (const float*)d_in[1];
    const float* W_proj = (const float*)d_in[2];
    const float* b_proj = (const float*)d_in[3];
    const float* W_ih   = (const float*)d_in[4];
    const float* b_ih   = (const float*)d_in[5];
    const float* W_hh   = (const float*)d_in[6];
    const float* b_hh   = (const float*)d_in[7];
    const float* W_fc   = (const float*)d_in[8];
    const float* b_fc   = (const float*)d_in[9];
    float* out = (float*)d_out;

    float* hbuf = (float*)d_ws;                                   // 2 * 64*512 floats
    unsigned long long* slots =
        (unsigned long long*)((char*)d_ws + 2 * B * H * sizeof(float)); // 2 * 64 slots
    float* hT = (float*)((char*)d_ws + 2 * B * H * sizeof(float)
                         + 128 * sizeof(unsigned long long));     // H*B floats (h transposed)

    init_kernel<<<128, 256, 0, stream>>>(z, W_proj, b_proj, hbuf, slots);

    for (int t = 0; t < T; ++t) {
        const float* hsrc = hbuf + (size_t)(t & 1) * (B * H);
        float* hdst = hbuf + (size_t)((t + 1) & 1) * (B * H);
        const unsigned long long* sread = (t == 0) ? nullptr : slots + ((t - 1) & 1) * B;
        unsigned long long* scur = slots + (t & 1) * B;

        gru_kernel<<<128, dim3(64, 4), 0, stream>>>(
            hsrc, hbuf, emb, sread, scur, W_ih, b_ih, W_hh, b_hh, hdst, hT);
        logits_kernel<<<500, dim3(64, 4), 0, stream>>>(hT, W_fc, b_fc, out, t, scur);
    }
}